// Round 1
// 1044.401 us; speedup vs baseline: 1.0333x; 1.0333x over previous
//
#include <hip/hip_runtime.h>
#include <hip/hip_bf16.h>
#include <stdint.h>

// LMHA: linear multi-head attention (elu+1 feature map), S=2048 B=16 D=1024 H=8 dh=128
// Pipeline: prep_h -> pack_w -> gemm_qkv (fused bias+elu+scatter) -> kv_kernel (kv state + z)
//           -> attn_kernel (num, den, divide) -> gemm_out (+bo)
// All GEMMs: bt-form C[m][n] = sum_k A[m][k] * W[n][k], bf16 in / fp32 acc,
// 128x128 block tile, 4 waves (2x2 of 64x64), MFMA 16x16x32 bf16.
// R1: GEMM core ported to m97 structure: global_load_lds width=16 into LINEAR
//     stride-32 LDS (no padding -- gload_lds dest must be wave-uniform + lane*16),
//     2 barriers per BK=32 step. Was reg-staged + stride-40 padded LDS.

typedef __bf16 bf16x8 __attribute__((ext_vector_type(8)));
typedef float f32x4 __attribute__((ext_vector_type(4)));

#define S_LEN 2048
#define B_SZ  16
#define D_MOD 1024
#define N_H   8
#define D_H   128

__device__ __forceinline__ short f2bf(float f) {
  __bf16 b = (__bf16)f;
  return __builtin_bit_cast(short, b);
}
__device__ __forceinline__ float bf2f(short s) {
  return (float)__builtin_bit_cast(__bf16, s);
}

// async global->LDS, 16B per lane. Dest must be wave-uniform base + lane*16.
__device__ __forceinline__ void gload_lds16(const short* g, short* l) {
  __builtin_amdgcn_global_load_lds(
      (__attribute__((address_space(1))) void*)(g),
      (__attribute__((address_space(3))) void*)(l), 16, 0, 0);
}

// ---------------- prep: h = bf16(x + pos_encoding) ----------------
__global__ void prep_h(const float* __restrict__ x, short* __restrict__ h) {
  size_t idx8 = (size_t)blockIdx.x * blockDim.x + threadIdx.x; // 8 elems / thread
  size_t base = idx8 * 8;                                      // < 33,554,432
  int d = (int)(base & 1023);
  int r = (int)(base >> 10);
  int s = r >> 4; // row = s*B + b
  float4 v0 = *(const float4*)(x + base);
  float4 v1 = *(const float4*)(x + base + 4);
  float vs[8] = {v0.x, v0.y, v0.z, v0.w, v1.x, v1.y, v1.z, v1.w};
  const float kdiv = -9.210340371976184f / 1024.0f; // -ln(10000)/D
  bf16x8 ov;
#pragma unroll
  for (int t = 0; t < 8; ++t) {
    int dc = d + t;
    float div = __expf((float)(dc & ~1) * kdiv);
    float ang = (float)s * div;
    float pe = (dc & 1) ? __cosf(ang) : __sinf(ang);
    ov[t] = (__bf16)(vs[t] + pe);
  }
  *(bf16x8*)(h + base) = ov;
}

// ---------------- pack weights to bf16: [Wq;Wk;Wv;Wo] = [4096,1024] ----------------
__global__ void pack_w(const float* __restrict__ Wq, const float* __restrict__ Wk,
                       const float* __restrict__ Wv, const float* __restrict__ Wo,
                       short* __restrict__ Wcat) {
  size_t i4 = (size_t)blockIdx.x * blockDim.x + threadIdx.x;
  size_t base = i4 * 4; // < 4,194,304
  const float* src;
  size_t off;
  if (base < 1048576)      { src = Wq; off = base; }
  else if (base < 2097152) { src = Wk; off = base - 1048576; }
  else if (base < 3145728) { src = Wv; off = base - 2097152; }
  else                     { src = Wo; off = base - 3145728; }
  float4 v = *(const float4*)(src + off);
  alignas(8) short o[4] = {f2bf(v.x), f2bf(v.y), f2bf(v.z), f2bf(v.w)};
  *(uint2*)(Wcat + base) = *(const uint2*)o;
}

// ---------------- shared GEMM core: 128x128 tile, bt-form (m97 structure) ----------
// A, W already offset to this block's 128-row bases. LDS linear [128][32] shorts.
// Per BK=32 step: 4x global_load_lds_dwordx4, 2 barriers, 8 ds_read_b128, 16 MFMA.
template <int K>
__device__ __forceinline__ void gemm_core_128(const short* __restrict__ A,
                                              const short* __restrict__ W,
                                              short* As, short* Ws,
                                              f32x4 (&acc)[4][4]) {
  const int tid = threadIdx.x;
  const int c8 = tid & 3, r0 = tid >> 2; // stage: row r0 (0..63), col c8*8
  const int lane = tid & 63;
  const int wm = (tid >> 6) & 1, wn = tid >> 7;
  const int l15 = lane & 15, quad = lane >> 4;

  // staging pointers: LDS offset = r0*32 + c8*8 shorts
  //   = (within wave) wave_base + lane*16B  -> satisfies gload_lds dest constraint
  const short* ga0 = A + (size_t)r0 * K + c8 * 8;
  const short* ga1 = ga0 + (size_t)64 * K;
  const short* gw0 = W + (size_t)r0 * K + c8 * 8;
  const short* gw1 = gw0 + (size_t)64 * K;
  short* la0 = As + r0 * 32 + c8 * 8;
  short* la1 = la0 + 64 * 32;
  short* lw0 = Ws + r0 * 32 + c8 * 8;
  short* lw1 = lw0 + 64 * 32;

  for (int k0 = 0; k0 < K; k0 += 32) {
    __syncthreads(); // all waves done reading LDS of previous step
    gload_lds16(ga0 + k0, la0);
    gload_lds16(ga1 + k0, la1);
    gload_lds16(gw0 + k0, lw0);
    gload_lds16(gw1 + k0, lw1);
    __syncthreads(); // drains vmcnt(0): LDS tiles ready
    bf16x8 af[4], wf[4];
#pragma unroll
    for (int i = 0; i < 4; ++i)
      af[i] = *(const bf16x8*)&As[(wm * 64 + i * 16 + l15) * 32 + quad * 8];
#pragma unroll
    for (int j = 0; j < 4; ++j)
      wf[j] = *(const bf16x8*)&Ws[(wn * 64 + j * 16 + l15) * 32 + quad * 8];
#pragma unroll
    for (int i = 0; i < 4; ++i)
#pragma unroll
      for (int j = 0; j < 4; ++j)
        acc[i][j] = __builtin_amdgcn_mfma_f32_16x16x32_bf16(af[i], wf[j], acc[i][j], 0, 0, 0);
  }
}

// ---------------- GEMM1: qkv = h @ Wqkv^T, fused bias + elu+1, scatter ----------------
// pq  -> [B,H,S,dh]   (s-major, for num GEMM A-operand)
// pkT -> [B,H,dh,S]   (transposed, K-contiguous for kv GEMM)
// vT  -> [B,H,dh,S]
__launch_bounds__(256)
__global__ void gemm_qkv(const short* __restrict__ h, const short* __restrict__ Wqkv,
                         const float* __restrict__ bq, const float* __restrict__ bk,
                         const float* __restrict__ bv,
                         short* __restrict__ pq, short* __restrict__ pkT,
                         short* __restrict__ vT) {
  __shared__ alignas(16) short As[128 * 32];
  __shared__ alignas(16) short Ws[128 * 32];
  const int bn = blockIdx.x; // 0..23  (N = 3072)
  const int bm = blockIdx.y; // 0..255 (M = 32768)
  const int rowBase = bm * 128, colBase = bn * 128;

  f32x4 acc[4][4] = {};
  gemm_core_128<1024>(h + (size_t)rowBase * 1024, Wqkv + (size_t)colBase * 1024, As, Ws, acc);

  const int tid = threadIdx.x;
  const int lane = tid & 63;
  const int wm = (tid >> 6) & 1, wn = tid >> 7;
  const int l15 = lane & 15, quad = lane >> 4;

  const int p = colBase >> 10;        // 0:q 1:k 2:v (uniform per block)
  const int hh = (colBase >> 7) & 7;  // head (uniform per block)
  const float* bias = (p == 0) ? bq : (p == 1) ? bk : bv;

#pragma unroll
  for (int j = 0; j < 4; ++j) {
    const int e = wn * 64 + j * 16 + l15; // 0..127
    const float bval = bias[hh * 128 + e];
#pragma unroll
    for (int i = 0; i < 4; ++i) {
#pragma unroll
      for (int r = 0; r < 4; ++r) {
        int mloc = wm * 64 + i * 16 + quad * 4 + r;
        int grow = rowBase + mloc;
        int s = grow >> 4, b = grow & 15;
        float v = acc[i][j][r] + bval;
        if (p == 0) {
          float u = v > 0.f ? v + 1.f : __expf(v); // elu(v)+1
          pq[(((size_t)b * N_H + hh) * S_LEN + s) * D_H + e] = f2bf(u);
        } else if (p == 1) {
          float u = v > 0.f ? v + 1.f : __expf(v);
          pkT[(((size_t)b * N_H + hh) * D_H + e) * S_LEN + s] = f2bf(u);
        } else {
          vT[(((size_t)b * N_H + hh) * D_H + e) * S_LEN + s] = f2bf(v);
        }
      }
    }
  }
}

// ---------------- kv state: kvT[bh][e][d] = sum_s vT[e][s]*pkT[d][s]; z[bh][d] ----------------
__launch_bounds__(256)
__global__ void kv_kernel(const short* __restrict__ pkT, const short* __restrict__ vT,
                          short* __restrict__ kvT, float* __restrict__ z) {
  __shared__ alignas(16) short As[128 * 32];
  __shared__ alignas(16) short Ws[128 * 32];
  const int bh = blockIdx.x; // 0..127
  const short* Abase = vT + (size_t)bh * D_H * S_LEN;  // rows = e
  const short* Wbase = pkT + (size_t)bh * D_H * S_LEN; // rows = d

  f32x4 acc[4][4] = {};
  gemm_core_128<2048>(Abase, Wbase, As, Ws, acc);

  const int tid = threadIdx.x;
  const int lane = tid & 63;
  const int wm = (tid >> 6) & 1, wn = tid >> 7;
  const int l15 = lane & 15, quad = lane >> 4;

#pragma unroll
  for (int j = 0; j < 4; ++j) {
    const int d = wn * 64 + j * 16 + l15;
#pragma unroll
    for (int i = 0; i < 4; ++i) {
#pragma unroll
      for (int r = 0; r < 4; ++r) {
        int e = wm * 64 + i * 16 + quad * 4 + r;
        kvT[(size_t)bh * (D_H * D_H) + (size_t)e * D_H + d] = f2bf(acc[i][j][r]);
      }
    }
  }
  // z[d] = sum_s pk[d][s]  (re-read pkT rows, L2-hot)
  __syncthreads();
  if (tid < 128) {
    const short* prow = Wbase + (size_t)tid * S_LEN;
    float sum = 0.f;
    for (int s = 0; s < S_LEN; s += 8) {
      bf16x8 vv = *(const bf16x8*)(prow + s);
#pragma unroll
      for (int t = 0; t < 8; ++t) sum += (float)vv[t];
    }
    z[bh * D_H + tid] = sum;
  }
}

// ---------------- num/den/divide: att = (pq @ kv) / (pq . z + eps) ----------------
__launch_bounds__(256)
__global__ void attn_kernel(const short* __restrict__ pq, const short* __restrict__ kvT,
                            const float* __restrict__ z, short* __restrict__ att) {
  __shared__ alignas(16) short As[128 * 32];
  __shared__ alignas(16) short Ws[128 * 32];
  __shared__ float den_lds[128];
  __shared__ float z_lds[128];
  const int s0 = blockIdx.x * 128; // 16 tiles over S
  const int bh = blockIdx.y;       // 0..127
  const int tid = threadIdx.x;
  if (tid < 128) z_lds[tid] = z[bh * D_H + tid];

  const short* Abase = pq + ((size_t)bh * S_LEN + s0) * D_H; // rows = s
  const short* Wbase = kvT + (size_t)bh * (D_H * D_H);       // rows = e, cols = d

  f32x4 acc[4][4] = {};
  gemm_core_128<128>(Abase, Wbase, As, Ws, acc);

  // den[s] = sum_d pq[s][d] * z[d] + eps
  __syncthreads();
  if (tid < 128) {
    const short* prow = Abase + (size_t)tid * D_H;
    float sum = 0.f;
#pragma unroll
    for (int d = 0; d < D_H; d += 8) {
      bf16x8 vv = *(const bf16x8*)(prow + d);
#pragma unroll
      for (int t = 0; t < 8; ++t) sum += (float)vv[t] * z_lds[d + t];
    }
    den_lds[tid] = sum + 1e-6f;
  }
  __syncthreads();

  const int lane = tid & 63;
  const int wm = (tid >> 6) & 1, wn = tid >> 7;
  const int l15 = lane & 15, quad = lane >> 4;
  const int b = bh >> 3, hd = bh & 7;
#pragma unroll
  for (int j = 0; j < 4; ++j) {
    const int e = wn * 64 + j * 16 + l15;
#pragma unroll
    for (int i = 0; i < 4; ++i) {
#pragma unroll
      for (int r = 0; r < 4; ++r) {
        int mloc = wm * 64 + i * 16 + quad * 4 + r; // s_local
        float a = acc[i][j][r] / den_lds[mloc];
        att[((size_t)(s0 + mloc) * B_SZ + b) * D_MOD + hd * D_H + e] = f2bf(a);
      }
    }
  }
}

// ---------------- out = att @ Wo^T + bo (fp32 out) ----------------
__launch_bounds__(256)
__global__ void gemm_out(const short* __restrict__ att, const short* __restrict__ WoB,
                         const float* __restrict__ bo, float* __restrict__ out) {
  __shared__ alignas(16) short As[128 * 32];
  __shared__ alignas(16) short Ws[128 * 32];
  const int bn = blockIdx.x; // 0..7
  const int bm = blockIdx.y; // 0..255
  const int rowBase = bm * 128, colBase = bn * 128;

  f32x4 acc[4][4] = {};
  gemm_core_128<1024>(att + (size_t)rowBase * 1024, WoB + (size_t)colBase * 1024, As, Ws, acc);

  const int tid = threadIdx.x;
  const int lane = tid & 63;
  const int wm = (tid >> 6) & 1, wn = tid >> 7;
  const int l15 = lane & 15, quad = lane >> 4;
#pragma unroll
  for (int j = 0; j < 4; ++j) {
    const int gcol = colBase + wn * 64 + j * 16 + l15;
    const float bval = bo[gcol];
#pragma unroll
    for (int i = 0; i < 4; ++i) {
#pragma unroll
      for (int r = 0; r < 4; ++r) {
        int grow = rowBase + wm * 64 + i * 16 + quad * 4 + r;
        out[(size_t)grow * 1024 + gcol] = acc[i][j][r] + bval;
      }
    }
  }
}

extern "C" void kernel_launch(void* const* d_in, const int* in_sizes, int n_in,
                              void* d_out, int out_size, void* d_ws, size_t ws_size,
                              hipStream_t stream) {
  const float* x  = (const float*)d_in[0];
  const float* Wq = (const float*)d_in[1];
  const float* bq = (const float*)d_in[2];
  const float* Wk = (const float*)d_in[3];
  const float* bk = (const float*)d_in[4];
  const float* Wv = (const float*)d_in[5];
  const float* bv = (const float*)d_in[6];
  const float* Wo = (const float*)d_in[7];
  const float* bo = (const float*)d_in[8];
  float* out = (float*)d_out;

  char* ws = (char*)d_ws;
  short* h    = (short*)(ws);                 // 67,108,864 B (reused as att later)
  short* Wcat = (short*)(ws + 67108864);      //  8,388,608 B ([Wq;Wk;Wv;Wo] bf16)
  short* pq   = (short*)(ws + 75497472);      // 67,108,864 B
  short* pkT  = (short*)(ws + 142606336);     // 67,108,864 B
  short* vT   = (short*)(ws + 209715200);     // 67,108,864 B
  short* kvT  = (short*)(ws + 276824064);     //  4,194,304 B
  float* z    = (float*)(ws + 281018368);     //     65,536 B

  prep_h<<<16384, 256, 0, stream>>>(x, h);
  pack_w<<<4096, 256, 0, stream>>>(Wq, Wk, Wv, Wo, Wcat);
  gemm_qkv<<<dim3(24, 256), 256, 0, stream>>>(h, Wcat, bq, bk, bv, pq, pkT, vT);
  kv_kernel<<<128, 256, 0, stream>>>(pkT, vT, kvT, z);
  attn_kernel<<<dim3(16, 128), 256, 0, stream>>>(pq, kvT, z, h /* att reuses h */);
  gemm_out<<<dim3(8, 256), 256, 0, stream>>>(h, Wcat + 3145728, bo, out);
}